// Round 14
// baseline (1577.775 us; speedup 1.0000x reference)
//
#include <hip/hip_runtime.h>
#include <math.h>

#define EPS 1e-6f

// Sliced-v2 pacing sweep: slice-ordered gather issue with soft s_waitcnt
// pacing. Measured so far: vmcnt(0)+barrier = 0.658GB but 558us (serialized);
// plain = 1.365GB, 383us (saturated fill path). This round brackets the
// middle: vmcnt(2) (tight) vs vmcnt(6) (loose) in one launch, per-dispatch
// counters separate them. Plain R5-shape kernel produces the final output.
#define SLICE_SHIFT 17
#define NSLICE 16

typedef int v4i __attribute__((ext_vector_type(4)));

struct __attribute__((packed, aligned(4))) Vert3 { float x, y, z; };

__device__ __forceinline__ float edge_cos_v(
    float p0x,float p0y,float p0z, float p1x,float p1y,float p1z,
    float p2x,float p2y,float p2z, float p3x,float p3y,float p3z)
{
    float ax = p1x - p0x, ay = p1y - p0y, az = p1z - p0z;
    float bx = p2x - p0x, by = p2y - p0y, bz = p2z - p0z;
    float cx = p3x - p0x, cy = p3y - p0y, cz = p3z - p0z;

    float al2 = ax*ax + ay*ay + az*az;
    float al1 = sqrtf(al2 + EPS);

    float bl2 = bx*bx + by*by + bz*bz;
    float bl1 = sqrtf(bl2 + EPS);
    float ab  = ax*bx + ay*by + az*bz;
    float cos1 = ab / (al1 * bl1 + EPS);
    float sin1 = sqrtf(1.0f - cos1*cos1 + EPS);
    float t1   = ab / (al2 + EPS);
    float cb1x = bx - ax*t1, cb1y = by - ay*t1, cb1z = bz - az*t1;
    float cb1l = bl1 * sin1;

    float cl2 = cx*cx + cy*cy + cz*cz;
    float cl1 = sqrtf(cl2 + EPS);
    float ac  = ax*cx + ay*cy + az*cz;
    float cos2 = ac / (al1 * cl1 + EPS);
    float sin2 = sqrtf(1.0f - cos2*cos2 + EPS);
    float t2   = ac / (al2 + EPS);
    float cb2x = cx - ax*t2, cb2y = cy - ay*t2, cb2z = cz - az*t2;
    float cb2l = cl1 * sin2;

    float num = cb1x*cb2x + cb1y*cb2y + cb1z*cb2z;
    return num / (cb1l * cb2l + EPS);
}

// ---------- soft-paced sliced gather, pacing depth as template param ----------
template <int NWAIT>
__global__ __launch_bounds__(256) void sf_v2_sliced(
    const Vert3* __restrict__ verts,
    const int* __restrict__ v0s, const int* __restrict__ v1s,
    const int* __restrict__ v2s, const int* __restrict__ v3s,
    float* __restrict__ cos_out, double* __restrict__ partials, int nquad)
{
    const int q      = blockIdx.x * blockDim.x + threadIdx.x;
    const bool valid = q < nquad;
    const int qq     = valid ? q : 0;

    v4i i0 = __builtin_nontemporal_load((const v4i*)v0s + qq);
    v4i i1 = __builtin_nontemporal_load((const v4i*)v1s + qq);
    v4i i2 = __builtin_nontemporal_load((const v4i*)v2s + qq);
    v4i i3 = __builtin_nontemporal_load((const v4i*)v3s + qq);

    int idx[16];
    idx[0]=i0.x;  idx[1]=i0.y;  idx[2]=i0.z;  idx[3]=i0.w;
    idx[4]=i1.x;  idx[5]=i1.y;  idx[6]=i1.z;  idx[7]=i1.w;
    idx[8]=i2.x;  idx[9]=i2.y;  idx[10]=i2.z; idx[11]=i2.w;
    idx[12]=i3.x; idx[13]=i3.y; idx[14]=i3.z; idx[15]=i3.w;

    float vx[16], vy[16], vz[16];

    #pragma unroll
    for (int s = 0; s < NSLICE; ++s) {
        #pragma unroll
        for (int r = 0; r < 16; ++r) {
            int sid = idx[r] >> SLICE_SHIFT;
            bool hit = (s == NSLICE - 1) ? (sid >= s) : (sid == s);
            if (hit) {
                Vert3 p = verts[idx[r]];
                vx[r] = p.x; vy[r] = p.y; vz[r] = p.z;
            }
        }
        // Soft pacing: allow NWAIT outstanding wave-loads; no barrier, no
        // full drain. Pacing-only (correctness waits are compiler-inserted
        // before first use of vx/vy/vz). "memory" pins issue order.
        if constexpr (NWAIT == 2)
            asm volatile("s_waitcnt vmcnt(2)" ::: "memory");
        else if constexpr (NWAIT == 6)
            asm volatile("s_waitcnt vmcnt(6)" ::: "memory");
        else
            asm volatile("s_waitcnt vmcnt(0)" ::: "memory");
    }

    double acc = 0.0;
    if (valid) {
        float cres[4];
        #pragma unroll
        for (int e = 0; e < 4; ++e)
            cres[e] = edge_cos_v(vx[e],vy[e],vz[e], vx[4+e],vy[4+e],vz[4+e],
                                 vx[8+e],vy[8+e],vz[8+e], vx[12+e],vy[12+e],vz[12+e]);
        int base = q << 2;
        __builtin_nontemporal_store(cres[0], cos_out + base + 0);
        __builtin_nontemporal_store(cres[1], cos_out + base + 1);
        __builtin_nontemporal_store(cres[2], cos_out + base + 2);
        __builtin_nontemporal_store(cres[3], cos_out + base + 3);
        float d0=cres[0]+1.0f, d1=cres[1]+1.0f, d2=cres[2]+1.0f, d3=cres[3]+1.0f;
        acc = (double)(d0*d0)+(double)(d1*d1)+(double)(d2*d2)+(double)(d3*d3);
    }

    #pragma unroll
    for (int off = 32; off > 0; off >>= 1) acc += __shfl_down(acc, off, 64);
    __shared__ double smem[4];
    int wid = threadIdx.x >> 6, lane = threadIdx.x & 63;
    if (lane == 0) smem[wid] = acc;
    __syncthreads();
    if (threadIdx.x == 0)
        partials[blockIdx.x] = smem[0]+smem[1]+smem[2]+smem[3];
}

// ---------- final output: exact R5 shape (validated, 383us) ----------
__global__ __launch_bounds__(256) void sf_main_plain(
    const Vert3* __restrict__ verts,
    const int* __restrict__ v0s, const int* __restrict__ v1s,
    const int* __restrict__ v2s, const int* __restrict__ v3s,
    float* __restrict__ cos_out, double* __restrict__ partials, int nquad)
{
    const int q      = blockIdx.x * blockDim.x + threadIdx.x;
    const bool valid = q < nquad;
    const int qq     = valid ? q : 0;

    v4i i0 = __builtin_nontemporal_load((const v4i*)v0s + qq);
    v4i i1 = __builtin_nontemporal_load((const v4i*)v1s + qq);
    v4i i2 = __builtin_nontemporal_load((const v4i*)v2s + qq);
    v4i i3 = __builtin_nontemporal_load((const v4i*)v3s + qq);

    double acc = 0.0;
    if (valid) {
        Vert3 p0[4] = { verts[i0.x], verts[i0.y], verts[i0.z], verts[i0.w] };
        Vert3 p1[4] = { verts[i1.x], verts[i1.y], verts[i1.z], verts[i1.w] };
        Vert3 p2[4] = { verts[i2.x], verts[i2.y], verts[i2.z], verts[i2.w] };
        Vert3 p3[4] = { verts[i3.x], verts[i3.y], verts[i3.z], verts[i3.w] };

        int base = q << 2;
        #pragma unroll
        for (int e = 0; e < 4; ++e) {
            float c = edge_cos_v(p0[e].x,p0[e].y,p0[e].z, p1[e].x,p1[e].y,p1[e].z,
                                 p2[e].x,p2[e].y,p2[e].z, p3[e].x,p3[e].y,p3[e].z);
            __builtin_nontemporal_store(c, cos_out + base + e);
            float d = c + 1.0f;
            acc += (double)(d*d);
        }
    }

    #pragma unroll
    for (int off = 32; off > 0; off >>= 1) acc += __shfl_down(acc, off, 64);
    __shared__ double smem[4];
    int wid = threadIdx.x >> 6, lane = threadIdx.x & 63;
    if (lane == 0) smem[wid] = acc;
    __syncthreads();
    if (threadIdx.x == 0)
        partials[blockIdx.x] = smem[0]+smem[1]+smem[2]+smem[3];
}

__global__ __launch_bounds__(256) void soft_flatten_reduce(
    const double* __restrict__ partials, int n, float* __restrict__ out)
{
    double acc = 0.0;
    for (int i = threadIdx.x; i < n; i += 256) acc += partials[i];
    #pragma unroll
    for (int off = 32; off > 0; off >>= 1) acc += __shfl_down(acc, off, 64);
    __shared__ double smem[4];
    int wid = threadIdx.x >> 6, lane = threadIdx.x & 63;
    if (lane == 0) smem[wid] = acc;
    __syncthreads();
    if (threadIdx.x == 0)
        out[0] = (float)(smem[0]+smem[1]+smem[2]+smem[3]);
}

extern "C" void kernel_launch(void* const* d_in, const int* in_sizes, int n_in,
                              void* d_out, int out_size, void* d_ws, size_t ws_size,
                              hipStream_t stream) {
    const Vert3* verts = (const Vert3*)d_in[0];
    const int*   v0s   = (const int*)d_in[1];
    const int*   v1s   = (const int*)d_in[2];
    const int*   v2s   = (const int*)d_in[3];
    const int*   v3s   = (const int*)d_in[4];

    const int nE    = in_sizes[1];        // 6,000,000
    const int nquad = nE >> 2;            // 1,500,000
    float* loss_out = (float*)d_out;
    float* cos_out  = (float*)d_out + 1;
    double* partials = (double*)d_ws;

    const int BLOCKS = (nquad + 255) / 256;   // 5860

    // Dispatch 1+2 (measurement): pacing sweep. Outputs overwritten below.
    sf_v2_sliced<2><<<BLOCKS, 256, 0, stream>>>(
        verts, v0s, v1s, v2s, v3s, cos_out, partials, nquad);
    sf_v2_sliced<6><<<BLOCKS, 256, 0, stream>>>(
        verts, v0s, v1s, v2s, v3s, cos_out, partials, nquad);

    // Dispatch 3 (final output): validated R5 shape.
    sf_main_plain<<<BLOCKS, 256, 0, stream>>>(
        verts, v0s, v1s, v2s, v3s, cos_out, partials, nquad);

    soft_flatten_reduce<<<1, 256, 0, stream>>>(partials, BLOCKS, loss_out);
}